// Round 17
// baseline (661.741 us; speedup 1.0000x reference)
//
#include <hip/hip_runtime.h>
#include <cstdint>
#include <cstddef>

#define N_NODES   100000
#define M_PAD     100096   // 782 * 128
#define DIM       256
#define NTYPES    6
#define M_EDGES   400000
#define TOTAL_E   2400000
#define EIGHTH_E  300000
#define NCOPY     8
#define NSCAN     800000   // NCOPY * N_NODES
#define SCAN_BLKS 782      // ceil(NSCAN/1024)
#define GEMM_BLKS 4704     // 98 * 48
#define CAP       20       // bucket capacity per (copy,tgt) slot

typedef _Float16 f16x8 __attribute__((ext_vector_type(8)));
typedef _Float16 f16x2 __attribute__((ext_vector_type(2)));
typedef float    f32x4 __attribute__((ext_vector_type(4)));

// ==== fused prep: [hist histBlk | b16 192 | gating 512 | a16 12512] =========
__global__ void prep_kernel(const float* __restrict__ x, _Float16* __restrict__ Ap,
                            const float* __restrict__ W, _Float16* __restrict__ Bp,
                            const float* __restrict__ Wp, const float* __restrict__ bp,
                            _Float16* __restrict__ gateb,
                            const int* __restrict__ edges, int* __restrict__ buf,
                            int histBlk)
{
    int b = blockIdx.x;
    if (b < histBlk){
        // ---- hist (ILP-8), exact-CSR fallback only ----
        int t0 = b * 256 + threadIdx.x;
        if (t0 >= EIGHTH_E) return;
        int copy = b & 7;
        #pragma unroll
        for (int j = 0; j < 8; ++j){
            int e = t0 + j * EIGHTH_E;
            int tgt = edges[(size_t)e * 2 + 1];
            atomicAdd(buf + copy * N_NODES + tgt, 1);
        }
    } else if (b < histBlk + 192){
        // ---- B16 = fp16(W) ----
        int tid = (b - histBlk) * 256 + threadIdx.x;
        int idx = tid << 3;
        const f32x4* pw = (const f32x4*)(W + idx);
        f32x4 v0 = __builtin_nontemporal_load(pw);
        f32x4 v1 = __builtin_nontemporal_load(pw + 1);
        f16x8 h;
        h[0]=(_Float16)v0[0]; h[1]=(_Float16)v0[1]; h[2]=(_Float16)v0[2]; h[3]=(_Float16)v0[3];
        h[4]=(_Float16)v1[0]; h[5]=(_Float16)v1[1]; h[6]=(_Float16)v1[2]; h[7]=(_Float16)v1[3];
        *(f16x8*)(Bp + idx) = h;
    } else if (b < histBlk + 704){
        // ---- gating table, fp64 trig ----
        __shared__ float semb[256];
        int p = b - histBlk - 192;     // 0..511
        int t = threadIdx.x;
        if (t < 127){
            double invf = exp(-log(10000.0) * (2.0 * t) / 254.0);
            double a = (double)p * invf;
            semb[t]       = (float)sin(a);
            semb[t + 127] = (float)cos(a);
        } else if (t >= 254){
            semb[t] = 0.0f;
        }
        __syncthreads();
        float z = bp[t];
        const float* wr = Wp + (size_t)t * 256;
        #pragma unroll 4
        for (int kq = 0; kq < 256; ++kq) z += semb[kq] * wr[kq];
        gateb[(size_t)p * 256 + t] = (_Float16)(2.0f / (1.0f + expf(-z)));
    } else {
        // ---- A16 = fp16(X) ----
        int tid = (b - histBlk - 704) * 256 + threadIdx.x;
        int idx = tid << 3;
        int row = idx >> 8;
        int k   = idx & 255;
        f16x8 h;
        if (row < N_NODES){
            const f32x4* px = (const f32x4*)(x + (size_t)row * DIM + k);
            f32x4 v0 = __builtin_nontemporal_load(px);
            f32x4 v1 = __builtin_nontemporal_load(px + 1);
            h[0]=(_Float16)v0[0]; h[1]=(_Float16)v0[1]; h[2]=(_Float16)v0[2]; h[3]=(_Float16)v0[3];
            h[4]=(_Float16)v1[0]; h[5]=(_Float16)v1[1]; h[6]=(_Float16)v1[2]; h[7]=(_Float16)v1[3];
        } else {
            #pragma unroll
            for (int j = 0; j < 8; ++j) h[j] = (_Float16)0.f;
        }
        *(f16x8*)(Ap + (size_t)row * 256 + k) = h;
    }
}

// ---- direct bucket scatter: NO hist/scan; cursor holds true counts --------
__global__ void scatter_direct(const int* __restrict__ edges, const int* __restrict__ posl,
                               int* __restrict__ cursor, unsigned* __restrict__ packed){
    int t0 = blockIdx.x * 256 + threadIdx.x;
    if (t0 >= EIGHTH_E) return;
    int copy = blockIdx.x & 7;
    #pragma unroll
    for (int j = 0; j < 8; ++j){
        int e = t0 + j * EIGHTH_E;
        int type = e / M_EDGES;
        int2 ed = *(const int2*)(edges + (size_t)e * 2);
        int lin = copy * N_NODES + ed.y;
        int p = atomicAdd(cursor + lin, 1);
        if (p < CAP)
            packed[(size_t)lin * CAP + p] =
                (unsigned)ed.x | ((unsigned)posl[e] << 17) | ((unsigned)type << 26);
    }
}

// ---- exact-CSR fallback: scans + scatter ----------------------------------
__global__ void scan1_kernel(int* __restrict__ buf, int* __restrict__ bsum){
    __shared__ int lds[256];
    int t = threadIdx.x;
    int base = blockIdx.x * 1024 + t * 4;
    int v[4]; int s = 0;
    #pragma unroll
    for (int j = 0; j < 4; ++j){
        int i = base + j;
        int val = (i < NSCAN) ? buf[i] : 0;
        v[j] = val; s += val;
    }
    lds[t] = s; __syncthreads();
    for (int d = 1; d < 256; d <<= 1){
        int xv = (t >= d) ? lds[t - d] : 0;
        __syncthreads();
        lds[t] += xv;
        __syncthreads();
    }
    int run = (t > 0) ? lds[t - 1] : 0;
    #pragma unroll
    for (int j = 0; j < 4; ++j){ int i = base + j; if (i < NSCAN) buf[i] = run; run += v[j]; }
    if (t == 255) bsum[blockIdx.x] = run;
}

__global__ void scan2_kernel(const int* __restrict__ bsum, int* __restrict__ ssum){
    __shared__ int lds[256];
    __shared__ int carry;
    int t = threadIdx.x;
    if (t == 0) carry = 0;
    __syncthreads();
    for (int ch = 0; ch < 4; ++ch){
        int idx = ch * 256 + t;
        int v = (idx < SCAN_BLKS) ? bsum[idx] : 0;
        lds[t] = v; __syncthreads();
        for (int d = 1; d < 256; d <<= 1){
            int xv = (t >= d) ? lds[t - d] : 0;
            __syncthreads();
            lds[t] += xv;
            __syncthreads();
        }
        int ex = carry + ((t > 0) ? lds[t - 1] : 0);
        if (idx < SCAN_BLKS) ssum[idx] = ex;
        __syncthreads();
        if (t == 255) carry += lds[255];
        __syncthreads();
    }
}

__global__ void scan3_kernel(int* __restrict__ buf, const int* __restrict__ ssum){
    int i = blockIdx.x * 256 + threadIdx.x;   // NSCAN exact (3125*256)
    buf[i] += ssum[i >> 10];
}

__global__ void scatter_kernel(const int* __restrict__ edges, const int* __restrict__ posl,
                               int* __restrict__ buf, unsigned* __restrict__ packed){
    int t0 = blockIdx.x * 256 + threadIdx.x;
    if (t0 >= EIGHTH_E) return;
    int copy = blockIdx.x & 7;
    #pragma unroll
    for (int j = 0; j < 8; ++j){
        int e = t0 + j * EIGHTH_E;
        int type = e / M_EDGES;
        int2 ed = *(const int2*)(edges + (size_t)e * 2);
        int p = atomicAdd(buf + copy * N_NODES + ed.y, 1);
        packed[p] = (unsigned)ed.x | ((unsigned)posl[e] << 17) | ((unsigned)type << 26);
    }
}

// ==== cooperative GEMM epilogue: 64-row shared stage, 1KB-contiguous nt stores
__device__ __forceinline__ void gemm_epilogue(
        char* smem, f32x4 (&acc)[4][4], const float* bbase, _Float16* propD,
        int t, size_t m0, int lane, int wid, int wr, int wc)
{
    float bv[4];
    #pragma unroll
    for (int n = 0; n < 4; ++n)
        bv[n] = bbase[(size_t)t * 256 + (wc << 6) + (n << 4) + (lane & 15)];

    const int q  = lane >> 4;          // 0..3
    const int li = lane & 15;
    const int cb = wid & 1;            // dim-block
    const int w2 = wid >> 1;           // 0..3

    #pragma unroll
    for (int ph = 0; ph < 2; ++ph){
        __syncthreads();
        if (wr == ph){
            #pragma unroll
            for (int m = 0; m < 4; ++m){
                #pragma unroll
                for (int n = 0; n < 4; ++n){
                    #pragma unroll
                    for (int j = 0; j < 4; ++j){
                        int lrow = (m << 4) + (q << 2) + j;          // (lrow>>2)&3 == q
                        int b    = (((wc << 6) + (n << 4) + li) << 1) ^ (q << 5);
                        *(_Float16*)(smem + lrow * 512 + b) =
                            (_Float16)(acc[m][n][j] + bv[n]);
                    }
                }
            }
        }
        __syncthreads();
        #pragma unroll
        for (int it = 0; it < 4; ++it){
            int r4   = w2 + (it << 2);          // 0..15
            int lrow = (r4 << 2) + q;           // (lrow>>2)&3 == r4&3
            int b    = ((cb << 8) + (li << 4)) ^ ((r4 & 3) << 5);
            f16x8 v = *(const f16x8*)(smem + lrow * 512 + b);
            size_t grow = m0 + (size_t)(ph << 6) + (size_t)lrow;
            _Float16* dst = propD + ((size_t)(cb * NTYPES + t) * M_PAD + grow) * 128
                            + (li << 3);
            __builtin_nontemporal_store(v, (f16x8*)dst);
        }
    }
}

__device__ __forceinline__ void gemm_mfma_phase(
        char* smem, f32x4 (&acc)[4][4], int lane, int wr, int wc)
{
    _Float16* sA = (_Float16*)smem;
    _Float16* sB = (_Float16*)(smem + 16384);
    #pragma unroll
    for (int ks = 0; ks < 2; ++ks){
        int slot = (ks << 6) + ((lane >> 4) << 4);
        f16x8 af[4];
        #pragma unroll
        for (int m = 0; m < 4; ++m){
            int rA = (wr << 6) + (m << 4) + (lane & 15);
            af[m] = *(const f16x8*)((const char*)sA + rA * 128 + (slot ^ ((rA & 7) << 4)));
        }
        #pragma unroll
        for (int n = 0; n < 4; ++n){
            int rB = (wc << 6) + (n << 4) + (lane & 15);
            f16x8 bfr = *(const f16x8*)((const char*)sB + rB * 128 + (slot ^ ((rB & 7) << 4)));
            #pragma unroll
            for (int m = 0; m < 4; ++m)
                acc[m][n] = __builtin_amdgcn_mfma_f32_16x16x32_f16(af[m], bfr, acc[m][n], 0, 0, 0);
        }
    }
}

// ---- GEMM (plan A/D): all 6 types, A from fp16 Ap via global_load_lds ------
__global__ __launch_bounds__(512, 4) void gemm_ap(
        const _Float16* __restrict__ Ap,
        const _Float16* __restrict__ Bp,
        const float* __restrict__ bbase,
        _Float16* __restrict__ propD)
{
    __shared__ __align__(16) char smem[49152];
    const int bid = blockIdx.x;
    const int g   = bid / 48;
    const int r   = bid - g * 48;
    const int rp  = g * 8 + (r & 7);
    const int t   = r >> 3;                 // 0..5
    if (rp >= 782) return;
    const int tid  = threadIdx.x;
    const int lane = tid & 63;
    const int wid  = tid >> 6;
    const int wr   = wid >> 2;
    const int wc   = wid & 3;
    const size_t m0 = (size_t)rp * 128;
    const _Float16* Bt = Bp + (size_t)t * 256 * 256;

    f32x4 acc[4][4];
    #pragma unroll
    for (int m = 0; m < 4; ++m)
        #pragma unroll
        for (int n = 0; n < 4; ++n)
            acc[m][n] = (f32x4){0.f, 0.f, 0.f, 0.f};

    const int sub  = lane >> 3;
    const int bib  = (lane & 7) << 4;
    const int soff = bib ^ (sub << 4);

    for (int kk = 0; kk < 4; ++kk){
        #pragma unroll
        for (int ci = 0; ci < 6; ++ci){
            int c = wid * 6 + ci;
            const char* gsrc;
            char* ldst;
            if (c < 16){
                gsrc = (const char*)(Ap + (m0 + (size_t)((c << 3) + sub)) * 256);
                ldst = (char*)smem + (c << 10);
            } else {
                int c2 = c - 16;
                gsrc = (const char*)(Bt + ((size_t)(c2 << 3) + sub) * 256);
                ldst = (char*)smem + 16384 + (c2 << 10);
            }
            __builtin_amdgcn_global_load_lds(
                (const __attribute__((address_space(1))) void*)(gsrc + (kk << 7) + soff),
                (__attribute__((address_space(3))) void*)ldst, 16, 0, 0);
        }
        __syncthreads();
        gemm_mfma_phase(smem, acc, lane, wr, wc);
        __syncthreads();
    }
    gemm_epilogue(smem, acc, bbase, propD, t, m0, lane, wid, wr, wc);
}

// ---- plan-B GEMM: A reg-staged from fp32 x (no Ap buffer needed) -----------
__global__ __launch_bounds__(512, 4) void gemm_dx(
        const float* __restrict__ x,
        const _Float16* __restrict__ Bp,
        const float* __restrict__ bbase,
        _Float16* __restrict__ propD)
{
    __shared__ __align__(16) char smem[49152];
    _Float16* sA = (_Float16*)smem;
    const int bid = blockIdx.x;
    const int g   = bid / 48;
    const int r   = bid - g * 48;
    const int rp  = g * 8 + (r & 7);
    const int t   = r >> 3;
    if (rp >= 782) return;
    const int tid  = threadIdx.x;
    const int lane = tid & 63;
    const int wid  = tid >> 6;
    const int wr   = wid >> 2;
    const int wc   = wid & 3;
    const size_t m0 = (size_t)rp * 128;
    const _Float16* Bt = Bp + (size_t)t * 256 * 256;

    f32x4 acc[4][4];
    #pragma unroll
    for (int m = 0; m < 4; ++m)
        #pragma unroll
        for (int n = 0; n < 4; ++n)
            acc[m][n] = (f32x4){0.f, 0.f, 0.f, 0.f};

    const int sub  = lane >> 3;
    const int bib  = (lane & 7) << 4;
    const int soff = bib ^ (sub << 4);

    for (int kk = 0; kk < 4; ++kk){
        #pragma unroll
        for (int ci = 0; ci < 6; ++ci){
            int c = wid * 6 + ci;
            if (c < 16){
                int rr = (c << 3) + sub;
                size_t grow = m0 + (size_t)rr;
                f32x4 u0 = (f32x4){0.f,0.f,0.f,0.f};
                f32x4 u1 = (f32x4){0.f,0.f,0.f,0.f};
                if (grow < N_NODES){
                    const float* px = x + grow * 256 + (kk << 6) + ((lane & 7) << 3);
                    u0 = *(const f32x4*)px;
                    u1 = *(const f32x4*)(px + 4);
                }
                f16x8 hv;
                hv[0]=(_Float16)u0[0]; hv[1]=(_Float16)u0[1];
                hv[2]=(_Float16)u0[2]; hv[3]=(_Float16)u0[3];
                hv[4]=(_Float16)u1[0]; hv[5]=(_Float16)u1[1];
                hv[6]=(_Float16)u1[2]; hv[7]=(_Float16)u1[3];
                *(f16x8*)((char*)sA + rr * 128 + (bib ^ (sub << 4))) = hv;
            } else {
                int c2 = c - 16;
                const char* gsrc = (const char*)(Bt + ((size_t)(c2 << 3) + sub) * 256);
                char* ldst = (char*)smem + 16384 + (c2 << 10);
                __builtin_amdgcn_global_load_lds(
                    (const __attribute__((address_space(1))) void*)(gsrc + (kk << 7) + soff),
                    (__attribute__((address_space(3))) void*)ldst, 16, 0, 0);
            }
        }
        __syncthreads();
        gemm_mfma_phase(smem, acc, lane, wr, wc);
        __syncthreads();
    }
    gemm_epilogue(smem, acc, bbase, propD, t, m0, lane, wid, wr, wc);
}

// ---- dim-half aggregation, ILP-4 ------------------------------------------
// cap>0: bucket layout, endoff holds true counts (segment = lin*cap, len<=cap)
// cap==0: exact CSR end-offsets (fallback)
__global__ void aggregate(const _Float16* __restrict__ propD, const _Float16* __restrict__ gate,
                          const unsigned* __restrict__ packed,
                          const int* __restrict__ endoff,
                          int cap, int dh, float* __restrict__ out)
{
    int tgt  = blockIdx.x * 4 + (threadIdx.x >> 6);
    int lane = threadIdx.x & 63;

    int st[8], P[9];
    P[0] = 0;
    #pragma unroll
    for (int c = 0; c < 8; ++c){
        int lin = c * N_NODES + tgt;
        int len, base;
        if (cap){
            len = endoff[lin]; if (len > cap) len = cap;
            base = lin * cap;
        } else {
            int a1 = endoff[lin];
            int a0 = lin ? endoff[lin - 1] : 0;
            len = a1 - a0; base = a0;
        }
        st[c] = base;
        P[c + 1] = P[c] + len;
    }
    int n = P[8];

    const _Float16* pbase = propD + (size_t)dh * NTYPES * M_PAD * 128;
    const _Float16* gbase = gate + dh * 128;

    float a0x = 0.f, a0y = 0.f, a1x = 0.f, a1y = 0.f;
    float a2x = 0.f, a2y = 0.f, a3x = 0.f, a3y = 0.f;

    for (int c0 = 0; c0 < n; c0 += 64){
        int e = c0 + lane;
        int idx = st[0] + e;
        #pragma unroll
        for (int c = 1; c < 8; ++c)
            if (e >= P[c]) idx = st[c] + (e - P[c]);
        unsigned wv = (e < n) ? packed[idx] : 0u;
        int m = n - c0; if (m > 64) m = 64;
        int e2 = 0;
        for (; e2 + 3 < m; e2 += 4){
            unsigned w[4];
            #pragma unroll
            for (int j = 0; j < 4; ++j)
                w[j] = (unsigned)__builtin_amdgcn_readlane((int)wv, e2 + j);
            f16x2 pv[4], gv[4];
            #pragma unroll
            for (int j = 0; j < 4; ++j){
                int src = (int)(w[j] & 0x1FFFFu);
                int pz  = (int)((w[j] >> 17) & 0x1FFu);
                int ty  = (int)(w[j] >> 26);
                pv[j] = *(const f16x2*)(pbase + ((size_t)ty * M_PAD + (size_t)src) * 128 + lane * 2);
                gv[j] = *(const f16x2*)(gbase + (size_t)pz * 256 + lane * 2);
            }
            a0x += (float)pv[0][0] * (float)gv[0][0];
            a0y += (float)pv[0][1] * (float)gv[0][1];
            a1x += (float)pv[1][0] * (float)gv[1][0];
            a1y += (float)pv[1][1] * (float)gv[1][1];
            a2x += (float)pv[2][0] * (float)gv[2][0];
            a2y += (float)pv[2][1] * (float)gv[2][1];
            a3x += (float)pv[3][0] * (float)gv[3][0];
            a3y += (float)pv[3][1] * (float)gv[3][1];
        }
        for (; e2 < m; ++e2){
            unsigned w0 = (unsigned)__builtin_amdgcn_readlane((int)wv, e2);
            int src = (int)(w0 & 0x1FFFFu);
            int pz  = (int)((w0 >> 17) & 0x1FFu);
            int ty  = (int)(w0 >> 26);
            f16x2 pv = *(const f16x2*)(pbase + ((size_t)ty * M_PAD + (size_t)src) * 128 + lane * 2);
            f16x2 gv = *(const f16x2*)(gbase + (size_t)pz * 256 + lane * 2);
            a0x += (float)pv[0] * (float)gv[0];
            a0y += (float)pv[1] * (float)gv[1];
        }
    }
    a0x += a1x + a2x + a3x;
    a0y += a1y + a2y + a3y;
    float inv = ((n == 0) ? 1.0f : (float)n) + 1e-8f;
    float2 rr = make_float2(a0x / inv, a0y / inv);
    *(float2*)(out + (size_t)tgt * DIM + dh * 128 + lane * 2) = rr;
}

extern "C" void kernel_launch(void* const* d_in, const int* in_sizes, int n_in,
                              void* d_out, int out_size, void* d_ws, size_t ws_size,
                              hipStream_t stream)
{
    const float* x     = (const float*)d_in[0];
    const float* W     = (const float*)d_in[1];
    const float* b     = (const float*)d_in[2];
    const float* Wp    = (const float*)d_in[3];
    const float* bp    = (const float*)d_in[4];
    const int*   edges = (const int*)d_in[5];
    const int*   posl  = (const int*)d_in[6];
    float* out = (float*)d_out;

    char* ws = (char*)d_ws;
    size_t o = 0;
    auto alloc = [&](size_t bytes){ void* p = ws + o; o += (bytes + 255) & ~(size_t)255; return p; };

    _Float16* propD = (_Float16*)alloc((size_t)2 * NTYPES * M_PAD * 128 * 2);  // 307.5 MB
    _Float16* Bp    = (_Float16*)alloc((size_t)NTYPES * 256 * 256 * 2);
    _Float16* gate  = (_Float16*)alloc((size_t)512 * 256 * 2);
    int*      buf   = (int*)alloc((size_t)NSCAN * 4);          // cnt/cursor/offsets
    int*      bsum  = (int*)alloc((size_t)SCAN_BLKS * 4 + 256);
    int*      ssum  = (int*)alloc((size_t)SCAN_BLKS * 4 + 256);
    size_t base = o;

    size_t capBytes = (size_t)NSCAN * CAP * 4;                 // 64 MB
    size_t apBytes  = (size_t)M_PAD * 256 * 2;                 // 51.25 MB
    bool planD = (ws_size >= base + capBytes + apBytes + (1u << 20));

    hipMemsetAsync(buf, 0, (size_t)NSCAN * 4, stream);

    if (planD){
        unsigned* packed = (unsigned*)alloc(capBytes);
        _Float16* Ap     = (_Float16*)alloc(apBytes);
        prep_kernel<<<704 + 12512, 256, 0, stream>>>(x, Ap, W, Bp, Wp, bp, gate,
                                                     edges, buf, 0);
        scatter_direct<<<1172, 256, 0, stream>>>(edges, posl, buf, packed);
        gemm_ap<<<GEMM_BLKS, 512, 0, stream>>>(Ap, Bp, b, propD);
        aggregate<<<25000, 256, 0, stream>>>(propD, gate, packed, buf, CAP, 0, out);
        aggregate<<<25000, 256, 0, stream>>>(propD, gate, packed, buf, CAP, 1, out);
    } else {
        unsigned* packed = (unsigned*)alloc((size_t)TOTAL_E * 4);
        bool planA = (ws_size >= o + apBytes + 1024);
        _Float16* Ap = planA ? (_Float16*)alloc(apBytes) : nullptr;
        int aBlk = planA ? 12512 : 0;

        prep_kernel<<<1876 + aBlk, 256, 0, stream>>>(x, Ap, W, Bp, Wp, bp, gate,
                                                     edges, buf, 1172);
        scan1_kernel<<<SCAN_BLKS, 256, 0, stream>>>(buf, bsum);
        scan2_kernel<<<1, 256, 0, stream>>>(bsum, ssum);
        scan3_kernel<<<3125, 256, 0, stream>>>(buf, ssum);
        scatter_kernel<<<1172, 256, 0, stream>>>(edges, posl, buf, packed);

        if (planA) gemm_ap<<<GEMM_BLKS, 512, 0, stream>>>(Ap, Bp, b, propD);
        else       gemm_dx<<<GEMM_BLKS, 512, 0, stream>>>(x, Bp, b, propD);

        aggregate<<<25000, 256, 0, stream>>>(propD, gate, packed, buf, 0, 0, out);
        aggregate<<<25000, 256, 0, stream>>>(propD, gate, packed, buf, 0, 1, out);
    }
}

// Round 18
// 614.177 us; speedup vs baseline: 1.0774x; 1.0774x over previous
//
#include <hip/hip_runtime.h>
#include <cstdint>
#include <cstddef>

#define N_NODES   100000
#define M_PAD     100096   // 782 * 128
#define DIM       256
#define NTYPES    6
#define M_EDGES   400000
#define TOTAL_E   2400000
#define EIGHTH_E  300000
#define NCOPY     8
#define NSCAN     800000   // NCOPY * N_NODES, copy-major: lin = c*N_NODES + tgt
#define SCAN_BLKS 782      // ceil(NSCAN/1024)
#define GEMM_BLKS 4704     // 98 * 48

typedef _Float16 f16x8 __attribute__((ext_vector_type(8)));
typedef _Float16 f16x2 __attribute__((ext_vector_type(2)));
typedef float    f32x4 __attribute__((ext_vector_type(4)));

// ==== fused prep, hist FIRST: [hist 1172 | b16 192 | gating 512 | a16 aBlk] =
__global__ void prep_kernel(const float* __restrict__ x, _Float16* __restrict__ Ap,
                            const float* __restrict__ W, _Float16* __restrict__ Bp,
                            const float* __restrict__ Wp, const float* __restrict__ bp,
                            _Float16* __restrict__ gateb,
                            const int* __restrict__ edges, int* __restrict__ buf,
                            int aBlk)
{
    int b = blockIdx.x;
    if (b < 1172){
        // ---- hist (ILP-8) ----
        int t0 = b * 256 + threadIdx.x;
        if (t0 >= EIGHTH_E) return;
        int copy = b & 7;
        #pragma unroll
        for (int j = 0; j < 8; ++j){
            int e = t0 + j * EIGHTH_E;
            int tgt = edges[(size_t)e * 2 + 1];
            atomicAdd(buf + copy * N_NODES + tgt, 1);
        }
    } else if (b < 1364){
        // ---- B16 = fp16(W) ----
        int tid = (b - 1172) * 256 + threadIdx.x;
        int idx = tid << 3;
        const f32x4* pw = (const f32x4*)(W + idx);
        f32x4 v0 = __builtin_nontemporal_load(pw);
        f32x4 v1 = __builtin_nontemporal_load(pw + 1);
        f16x8 h;
        h[0]=(_Float16)v0[0]; h[1]=(_Float16)v0[1]; h[2]=(_Float16)v0[2]; h[3]=(_Float16)v0[3];
        h[4]=(_Float16)v1[0]; h[5]=(_Float16)v1[1]; h[6]=(_Float16)v1[2]; h[7]=(_Float16)v1[3];
        *(f16x8*)(Bp + idx) = h;
    } else if (b < 1876){
        // ---- gating table, fp64 trig ----
        __shared__ float semb[256];
        int p = b - 1364;     // 0..511
        int t = threadIdx.x;
        if (t < 127){
            double invf = exp(-log(10000.0) * (2.0 * t) / 254.0);
            double a = (double)p * invf;
            semb[t]       = (float)sin(a);
            semb[t + 127] = (float)cos(a);
        } else if (t >= 254){
            semb[t] = 0.0f;
        }
        __syncthreads();
        float z = bp[t];
        const float* wr = Wp + (size_t)t * 256;
        #pragma unroll 4
        for (int kq = 0; kq < 256; ++kq) z += semb[kq] * wr[kq];
        gateb[(size_t)p * 256 + t] = (_Float16)(2.0f / (1.0f + expf(-z)));
    } else {
        // ---- A16 = fp16(X) ----
        int tid = (b - 1876) * 256 + threadIdx.x;
        int idx = tid << 3;
        int row = idx >> 8;
        int k   = idx & 255;
        f16x8 h;
        if (row < N_NODES){
            const f32x4* px = (const f32x4*)(x + (size_t)row * DIM + k);
            f32x4 v0 = __builtin_nontemporal_load(px);
            f32x4 v1 = __builtin_nontemporal_load(px + 1);
            h[0]=(_Float16)v0[0]; h[1]=(_Float16)v0[1]; h[2]=(_Float16)v0[2]; h[3]=(_Float16)v0[3];
            h[4]=(_Float16)v1[0]; h[5]=(_Float16)v1[1]; h[6]=(_Float16)v1[2]; h[7]=(_Float16)v1[3];
        } else {
            #pragma unroll
            for (int j = 0; j < 8; ++j) h[j] = (_Float16)0.f;
        }
        *(f16x8*)(Ap + (size_t)row * 256 + k) = h;
    }
}

__global__ void scan1_kernel(int* __restrict__ buf, int* __restrict__ bsum){
    __shared__ int lds[256];
    int t = threadIdx.x;
    int base = blockIdx.x * 1024 + t * 4;
    int v[4]; int s = 0;
    #pragma unroll
    for (int j = 0; j < 4; ++j){
        int i = base + j;
        int val = (i < NSCAN) ? buf[i] : 0;
        v[j] = val; s += val;
    }
    lds[t] = s; __syncthreads();
    for (int d = 1; d < 256; d <<= 1){
        int xv = (t >= d) ? lds[t - d] : 0;
        __syncthreads();
        lds[t] += xv;
        __syncthreads();
    }
    int run = (t > 0) ? lds[t - 1] : 0;
    #pragma unroll
    for (int j = 0; j < 4; ++j){ int i = base + j; if (i < NSCAN) buf[i] = run; run += v[j]; }
    if (t == 255) bsum[blockIdx.x] = run;
}

__global__ void scan2_kernel(const int* __restrict__ bsum, int* __restrict__ ssum){
    __shared__ int lds[256];
    __shared__ int carry;
    int t = threadIdx.x;
    if (t == 0) carry = 0;
    __syncthreads();
    for (int ch = 0; ch < 4; ++ch){
        int idx = ch * 256 + t;
        int v = (idx < SCAN_BLKS) ? bsum[idx] : 0;
        lds[t] = v; __syncthreads();
        for (int d = 1; d < 256; d <<= 1){
            int xv = (t >= d) ? lds[t - d] : 0;
            __syncthreads();
            lds[t] += xv;
            __syncthreads();
        }
        int ex = carry + ((t > 0) ? lds[t - 1] : 0);
        if (idx < SCAN_BLKS) ssum[idx] = ex;
        __syncthreads();
        if (t == 255) carry += lds[255];
        __syncthreads();
    }
}

__global__ void scan3_kernel(int* __restrict__ buf, const int* __restrict__ ssum){
    int i = blockIdx.x * 256 + threadIdx.x;   // NSCAN exact (3125*256)
    buf[i] += ssum[i >> 10];
}

// ---- standalone scatter (ILP-8) -------------------------------------------
__global__ void scatter_kernel(const int* __restrict__ edges, const int* __restrict__ posl,
                               int* __restrict__ buf, unsigned* __restrict__ packed){
    int t0 = blockIdx.x * 256 + threadIdx.x;
    if (t0 >= EIGHTH_E) return;
    int copy = blockIdx.x & 7;
    #pragma unroll
    for (int j = 0; j < 8; ++j){
        int e = t0 + j * EIGHTH_E;
        int type = e / M_EDGES;
        int2 ed = *(const int2*)(edges + (size_t)e * 2);
        int p = atomicAdd(buf + copy * N_NODES + ed.y, 1);
        packed[p] = (unsigned)ed.x | ((unsigned)posl[e] << 17) | ((unsigned)type << 26);
    }
}

// ==== cooperative GEMM epilogue: 64-row shared stage, 1KB-contiguous nt stores
__device__ __forceinline__ void gemm_epilogue(
        char* smem, f32x4 (&acc)[4][4], const float* bbase, _Float16* propD,
        int t, size_t m0, int lane, int wid, int wr, int wc)
{
    float bv[4];
    #pragma unroll
    for (int n = 0; n < 4; ++n)
        bv[n] = bbase[(size_t)t * 256 + (wc << 6) + (n << 4) + (lane & 15)];

    const int q  = lane >> 4;          // 0..3
    const int li = lane & 15;
    const int cb = wid & 1;            // dim-block
    const int w2 = wid >> 1;           // 0..3

    #pragma unroll
    for (int ph = 0; ph < 2; ++ph){
        __syncthreads();
        if (wr == ph){
            #pragma unroll
            for (int m = 0; m < 4; ++m){
                #pragma unroll
                for (int n = 0; n < 4; ++n){
                    #pragma unroll
                    for (int j = 0; j < 4; ++j){
                        int lrow = (m << 4) + (q << 2) + j;          // (lrow>>2)&3 == q
                        int b    = (((wc << 6) + (n << 4) + li) << 1) ^ (q << 5);
                        *(_Float16*)(smem + lrow * 512 + b) =
                            (_Float16)(acc[m][n][j] + bv[n]);
                    }
                }
            }
        }
        __syncthreads();
        #pragma unroll
        for (int it = 0; it < 4; ++it){
            int r4   = w2 + (it << 2);          // 0..15
            int lrow = (r4 << 2) + q;           // (lrow>>2)&3 == r4&3
            int b    = ((cb << 8) + (li << 4)) ^ ((r4 & 3) << 5);
            f16x8 v = *(const f16x8*)(smem + lrow * 512 + b);
            size_t grow = m0 + (size_t)(ph << 6) + (size_t)lrow;
            _Float16* dst = propD + ((size_t)(cb * NTYPES + t) * M_PAD + grow) * 128
                            + (li << 3);
            __builtin_nontemporal_store(v, (f16x8*)dst);
        }
    }
}

__device__ __forceinline__ void gemm_mfma_phase(
        char* smem, f32x4 (&acc)[4][4], int lane, int wr, int wc)
{
    _Float16* sA = (_Float16*)smem;
    _Float16* sB = (_Float16*)(smem + 16384);
    #pragma unroll
    for (int ks = 0; ks < 2; ++ks){
        int slot = (ks << 6) + ((lane >> 4) << 4);
        f16x8 af[4];
        #pragma unroll
        for (int m = 0; m < 4; ++m){
            int rA = (wr << 6) + (m << 4) + (lane & 15);
            af[m] = *(const f16x8*)((const char*)sA + rA * 128 + (slot ^ ((rA & 7) << 4)));
        }
        #pragma unroll
        for (int n = 0; n < 4; ++n){
            int rB = (wc << 6) + (n << 4) + (lane & 15);
            f16x8 bfr = *(const f16x8*)((const char*)sB + rB * 128 + (slot ^ ((rB & 7) << 4)));
            #pragma unroll
            for (int m = 0; m < 4; ++m)
                acc[m][n] = __builtin_amdgcn_mfma_f32_16x16x32_f16(af[m], bfr, acc[m][n], 0, 0, 0);
        }
    }
}

// ---- plan-A GEMM: all 6 types, A from fp16 Ap via global_load_lds ----------
__global__ __launch_bounds__(512, 4) void gemm_ap(
        const _Float16* __restrict__ Ap,
        const _Float16* __restrict__ Bp,
        const float* __restrict__ bbase,
        _Float16* __restrict__ propD)
{
    __shared__ __align__(16) char smem[49152];
    const int bid = blockIdx.x;
    const int g   = bid / 48;
    const int r   = bid - g * 48;
    const int rp  = g * 8 + (r & 7);
    const int t   = r >> 3;                 // 0..5
    if (rp >= 782) return;
    const int tid  = threadIdx.x;
    const int lane = tid & 63;
    const int wid  = tid >> 6;
    const int wr   = wid >> 2;
    const int wc   = wid & 3;
    const size_t m0 = (size_t)rp * 128;
    const _Float16* Bt = Bp + (size_t)t * 256 * 256;

    f32x4 acc[4][4];
    #pragma unroll
    for (int m = 0; m < 4; ++m)
        #pragma unroll
        for (int n = 0; n < 4; ++n)
            acc[m][n] = (f32x4){0.f, 0.f, 0.f, 0.f};

    const int sub  = lane >> 3;
    const int bib  = (lane & 7) << 4;
    const int soff = bib ^ (sub << 4);

    for (int kk = 0; kk < 4; ++kk){
        #pragma unroll
        for (int ci = 0; ci < 6; ++ci){
            int c = wid * 6 + ci;
            const char* gsrc;
            char* ldst;
            if (c < 16){
                gsrc = (const char*)(Ap + (m0 + (size_t)((c << 3) + sub)) * 256);
                ldst = (char*)smem + (c << 10);
            } else {
                int c2 = c - 16;
                gsrc = (const char*)(Bt + ((size_t)(c2 << 3) + sub) * 256);
                ldst = (char*)smem + 16384 + (c2 << 10);
            }
            __builtin_amdgcn_global_load_lds(
                (const __attribute__((address_space(1))) void*)(gsrc + (kk << 7) + soff),
                (__attribute__((address_space(3))) void*)ldst, 16, 0, 0);
        }
        __syncthreads();
        gemm_mfma_phase(smem, acc, lane, wr, wc);
        __syncthreads();
    }
    gemm_epilogue(smem, acc, bbase, propD, t, m0, lane, wid, wr, wc);
}

// ---- plan-B GEMM: A reg-staged from fp32 x (no Ap buffer needed) -----------
__global__ __launch_bounds__(512, 4) void gemm_dx(
        const float* __restrict__ x,
        const _Float16* __restrict__ Bp,
        const float* __restrict__ bbase,
        _Float16* __restrict__ propD)
{
    __shared__ __align__(16) char smem[49152];
    _Float16* sA = (_Float16*)smem;
    const int bid = blockIdx.x;
    const int g   = bid / 48;
    const int r   = bid - g * 48;
    const int rp  = g * 8 + (r & 7);
    const int t   = r >> 3;
    if (rp >= 782) return;
    const int tid  = threadIdx.x;
    const int lane = tid & 63;
    const int wid  = tid >> 6;
    const int wr   = wid >> 2;
    const int wc   = wid & 3;
    const size_t m0 = (size_t)rp * 128;
    const _Float16* Bt = Bp + (size_t)t * 256 * 256;

    f32x4 acc[4][4];
    #pragma unroll
    for (int m = 0; m < 4; ++m)
        #pragma unroll
        for (int n = 0; n < 4; ++n)
            acc[m][n] = (f32x4){0.f, 0.f, 0.f, 0.f};

    const int sub  = lane >> 3;
    const int bib  = (lane & 7) << 4;
    const int soff = bib ^ (sub << 4);

    for (int kk = 0; kk < 4; ++kk){
        #pragma unroll
        for (int ci = 0; ci < 6; ++ci){
            int c = wid * 6 + ci;
            if (c < 16){
                int rr = (c << 3) + sub;
                size_t grow = m0 + (size_t)rr;
                f32x4 u0 = (f32x4){0.f,0.f,0.f,0.f};
                f32x4 u1 = (f32x4){0.f,0.f,0.f,0.f};
                if (grow < N_NODES){
                    const float* px = x + grow * 256 + (kk << 6) + ((lane & 7) << 3);
                    u0 = *(const f32x4*)px;
                    u1 = *(const f32x4*)(px + 4);
                }
                f16x8 hv;
                hv[0]=(_Float16)u0[0]; hv[1]=(_Float16)u0[1];
                hv[2]=(_Float16)u0[2]; hv[3]=(_Float16)u0[3];
                hv[4]=(_Float16)u1[0]; hv[5]=(_Float16)u1[1];
                hv[6]=(_Float16)u1[2]; hv[7]=(_Float16)u1[3];
                *(f16x8*)((char*)sA + rr * 128 + (bib ^ (sub << 4))) = hv;
            } else {
                int c2 = c - 16;
                const char* gsrc = (const char*)(Bt + ((size_t)(c2 << 3) + sub) * 256);
                char* ldst = (char*)smem + 16384 + (c2 << 10);
                __builtin_amdgcn_global_load_lds(
                    (const __attribute__((address_space(1))) void*)(gsrc + (kk << 7) + soff),
                    (__attribute__((address_space(3))) void*)ldst, 16, 0, 0);
            }
        }
        __syncthreads();
        gemm_mfma_phase(smem, acc, lane, wr, wc);
        __syncthreads();
    }
    gemm_epilogue(smem, acc, bbase, propD, t, m0, lane, wid, wr, wc);
}

// ---- dim-half aggregation: ALL 6 types, L3-resident prop-half, ILP-8 ------
__global__ void aggregate(const _Float16* __restrict__ propD, const _Float16* __restrict__ gate,
                          const unsigned* __restrict__ packed,
                          const int* __restrict__ endoff,
                          int dh, float* __restrict__ out)
{
    int tgt  = blockIdx.x * 4 + (threadIdx.x >> 6);
    int lane = threadIdx.x & 63;

    int st[8], P[9];
    P[0] = 0;
    #pragma unroll
    for (int c = 0; c < 8; ++c){
        int lin = c * N_NODES + tgt;
        int a1 = endoff[lin];
        int a0 = lin ? endoff[lin - 1] : 0;
        st[c] = a0;
        P[c + 1] = P[c] + (a1 - a0);
    }
    int n = P[8];

    const _Float16* pbase = propD + (size_t)dh * NTYPES * M_PAD * 128;
    const _Float16* gbase = gate + dh * 128;

    float ax[8], ay[8];
    #pragma unroll
    for (int j = 0; j < 8; ++j){ ax[j] = 0.f; ay[j] = 0.f; }

    for (int c0 = 0; c0 < n; c0 += 64){
        int e = c0 + lane;
        int idx = st[0] + e;
        #pragma unroll
        for (int c = 1; c < 8; ++c)
            if (e >= P[c]) idx = st[c] + (e - P[c]);
        unsigned wv = (e < n) ? packed[idx] : 0u;
        int m = n - c0; if (m > 64) m = 64;
        int e2 = 0;
        for (; e2 + 7 < m; e2 += 8){
            unsigned w[8];
            #pragma unroll
            for (int j = 0; j < 8; ++j)
                w[j] = (unsigned)__builtin_amdgcn_readlane((int)wv, e2 + j);
            f16x2 pv[8], gv[8];
            #pragma unroll
            for (int j = 0; j < 8; ++j){
                int src = (int)(w[j] & 0x1FFFFu);
                int pz  = (int)((w[j] >> 17) & 0x1FFu);
                int ty  = (int)(w[j] >> 26);
                pv[j] = *(const f16x2*)(pbase + ((size_t)ty * M_PAD + (size_t)src) * 128 + lane * 2);
                gv[j] = *(const f16x2*)(gbase + (size_t)pz * 256 + lane * 2);
            }
            #pragma unroll
            for (int j = 0; j < 8; ++j){
                ax[j] += (float)pv[j][0] * (float)gv[j][0];
                ay[j] += (float)pv[j][1] * (float)gv[j][1];
            }
        }
        for (; e2 + 3 < m; e2 += 4){
            unsigned w[4];
            #pragma unroll
            for (int j = 0; j < 4; ++j)
                w[j] = (unsigned)__builtin_amdgcn_readlane((int)wv, e2 + j);
            f16x2 pv[4], gv[4];
            #pragma unroll
            for (int j = 0; j < 4; ++j){
                int src = (int)(w[j] & 0x1FFFFu);
                int pz  = (int)((w[j] >> 17) & 0x1FFu);
                int ty  = (int)(w[j] >> 26);
                pv[j] = *(const f16x2*)(pbase + ((size_t)ty * M_PAD + (size_t)src) * 128 + lane * 2);
                gv[j] = *(const f16x2*)(gbase + (size_t)pz * 256 + lane * 2);
            }
            #pragma unroll
            for (int j = 0; j < 4; ++j){
                ax[j] += (float)pv[j][0] * (float)gv[j][0];
                ay[j] += (float)pv[j][1] * (float)gv[j][1];
            }
        }
        for (; e2 < m; ++e2){
            unsigned w0 = (unsigned)__builtin_amdgcn_readlane((int)wv, e2);
            int src = (int)(w0 & 0x1FFFFu);
            int pz  = (int)((w0 >> 17) & 0x1FFu);
            int ty  = (int)(w0 >> 26);
            f16x2 pv = *(const f16x2*)(pbase + ((size_t)ty * M_PAD + (size_t)src) * 128 + lane * 2);
            f16x2 gv = *(const f16x2*)(gbase + (size_t)pz * 256 + lane * 2);
            ax[0] += (float)pv[0] * (float)gv[0];
            ay[0] += (float)pv[1] * (float)gv[1];
        }
    }
    float sx = (ax[0] + ax[1]) + (ax[2] + ax[3]) + ((ax[4] + ax[5]) + (ax[6] + ax[7]));
    float sy = (ay[0] + ay[1]) + (ay[2] + ay[3]) + ((ay[4] + ay[5]) + (ay[6] + ay[7]));
    float inv = ((n == 0) ? 1.0f : (float)n) + 1e-8f;
    float2 rr = make_float2(sx / inv, sy / inv);
    *(float2*)(out + (size_t)tgt * DIM + dh * 128 + lane * 2) = rr;
}

extern "C" void kernel_launch(void* const* d_in, const int* in_sizes, int n_in,
                              void* d_out, int out_size, void* d_ws, size_t ws_size,
                              hipStream_t stream)
{
    const float* x     = (const float*)d_in[0];
    const float* W     = (const float*)d_in[1];
    const float* b     = (const float*)d_in[2];
    const float* Wp    = (const float*)d_in[3];
    const float* bp    = (const float*)d_in[4];
    const int*   edges = (const int*)d_in[5];
    const int*   posl  = (const int*)d_in[6];
    float* out = (float*)d_out;

    char* ws = (char*)d_ws;
    size_t o = 0;
    auto alloc = [&](size_t bytes){ void* p = ws + o; o += (bytes + 255) & ~(size_t)255; return p; };

    _Float16* propD = (_Float16*)alloc((size_t)2 * NTYPES * M_PAD * 128 * 2);  // 307.5 MB
    _Float16* Bp    = (_Float16*)alloc((size_t)NTYPES * 256 * 256 * 2);
    _Float16* gate  = (_Float16*)alloc((size_t)512 * 256 * 2);
    int*      buf   = (int*)alloc((size_t)NSCAN * 4);          // cnt->offs->ends
    unsigned* packed= (unsigned*)alloc((size_t)TOTAL_E * 4);
    int*      bsum  = (int*)alloc((size_t)SCAN_BLKS * 4 + 256);
    int*      ssum  = (int*)alloc((size_t)SCAN_BLKS * 4 + 256);

    size_t apBytes = (size_t)M_PAD * 256 * 2;                  // 51.25 MB
    bool planA = (ws_size >= o + apBytes + 1024);
    _Float16* Ap = planA ? (_Float16*)alloc(apBytes) : nullptr;
    int aBlk = planA ? 12512 : 0;

    hipMemsetAsync(buf, 0, (size_t)NSCAN * 4, stream);

    prep_kernel<<<1876 + aBlk, 256, 0, stream>>>(x, Ap, W, Bp, Wp, bp, gate,
                                                 edges, buf, aBlk);
    scan1_kernel<<<SCAN_BLKS, 256, 0, stream>>>(buf, bsum);
    scan2_kernel<<<1, 256, 0, stream>>>(bsum, ssum);
    scan3_kernel<<<3125, 256, 0, stream>>>(buf, ssum);
    scatter_kernel<<<1172, 256, 0, stream>>>(edges, posl, buf, packed);

    if (planA) gemm_ap<<<GEMM_BLKS, 512, 0, stream>>>(Ap, Bp, b, propD);
    else       gemm_dx<<<GEMM_BLKS, 512, 0, stream>>>(x, Bp, b, propD);

    aggregate<<<25000, 256, 0, stream>>>(propD, gate, packed, buf, 0, out);
    aggregate<<<25000, 256, 0, stream>>>(propD, gate, packed, buf, 1, out);
}